// Round 3
// baseline (12825.670 us; speedup 1.0000x reference)
//
#include <hip/hip_runtime.h>
#include <stdint.h>

// R3: single-workgroup-per-cluster persistent LSTM for MI355X.
// 64 WGs x 512 threads (8 waves). Each WG owns 16 batch rows and the FULL
// 288x1024 weight slice in registers (288 VGPRs/lane bf16 B-frags).
// Recurrence state (c) in registers (MFMA C/D layout); h exchanged through
// LDS with __syncthreads only — no cross-WG communication of any kind
// (R1 deadlocked on cross-WG co-residency; R2's cooperative launch failed
// to launch: absmax equaled the all-zero-output value).
// y = h @ W_out done via MFMA on wave 0 (W_out staged as B-frags).

#define B_TOTAL   1024
#define H_DIM     256
#define F_WARM    32
#define F_AUTO    24
#define O_DIM     8
#define T_WARM    512
#define T_TOTAL   1024
#define N4H       1024
#define A_STRIDE  296   // 288 K padded (592 B rows, 16B-aligned fragments)

typedef __attribute__((ext_vector_type(8))) short short8;
typedef __attribute__((ext_vector_type(4))) float float4v;

__device__ __forceinline__ short f2bf(float x) {
    union { float f; uint32_t u; } v; v.f = x;
    uint32_t r = v.u + 0x7FFFu + ((v.u >> 16) & 1u);   // RNE
    return (short)(r >> 16);
}
__device__ __forceinline__ float sigmoid_(float x) {
    return 1.0f / (1.0f + __expf(-x));
}
__device__ __forceinline__ float tanh_(float x) {
    float e = __expf(-2.0f * fabsf(x));
    float t = (1.0f - e) / (1.0f + e);
    return x >= 0.0f ? t : -t;
}

__global__ __launch_bounds__(512, 1)
void lstm_wg(const float* __restrict__ c0, const float* __restrict__ h0,
             const float* __restrict__ warm, const float* __restrict__ autoin,
             const float* __restrict__ W_ih, const float* __restrict__ W_hh,
             const float* __restrict__ bvec, const float* __restrict__ W_out,
             const float* __restrict__ b_out, float* __restrict__ out)
{
    const int tid  = threadIdx.x;
    const int w    = tid >> 6;        // wave 0..7 -> hidden block w*32
    const int l    = tid & 63;
    const int n16  = l & 15;          // MFMA n (B/D col) / A row (m)
    const int kg   = l >> 4;          // k-group 0..3
    const int row0 = blockIdx.x * 16; // batch rows [row0, row0+16)

    __shared__ __align__(16) short Alds[16 * A_STRIDE];  // [x(32) | h(256) | pad]
    __shared__ float ybuf[16 * O_DIM];

    // ---- one-time: weight slice -> registers (bf16 MFMA B-frags) ----
    // wave w owns hidden units [w*32, w*32+32) for all 4 gates:
    //   col(g,j) = g*256 + w*32 + j*16 + n16
    short8 bw[4][2][9];
    float  bias[4][2];
    #pragma unroll
    for (int g = 0; g < 4; ++g) {
        #pragma unroll
        for (int j = 0; j < 2; ++j) {
            const int col = g * 256 + w * 32 + j * 16 + n16;
            bias[g][j] = bvec[col];
            #pragma unroll
            for (int kk = 0; kk < 9; ++kk) {
                short8 f;
                #pragma unroll
                for (int i = 0; i < 8; ++i) {
                    const int k = kk * 32 + kg * 8 + i;     // K index 0..287
                    const float wv = (k < F_WARM) ? W_ih[k * N4H + col]
                                                  : W_hh[(k - F_WARM) * N4H + col];
                    f[i] = f2bf(wv);
                }
                bw[g][j][kk] = f;
            }
        }
    }

    // ---- wave 0: W_out as B-frags (B[k][n], n=lane&15, k=(lane>>4)*8+i) ----
    short8 wo[8];
    float  bout_r = 0.0f;
    if (w == 0) {
        bout_r = (n16 < O_DIM) ? b_out[n16] : 0.0f;
        #pragma unroll
        for (int kk = 0; kk < 8; ++kk) {
            short8 f;
            #pragma unroll
            for (int i = 0; i < 8; ++i) {
                const int k = kk * 32 + kg * 8 + i;         // hidden index 0..255
                f[i] = (n16 < O_DIM) ? f2bf(W_out[k * O_DIM + n16]) : (short)0;
            }
            wo[kk] = f;
        }
    }

    // ---- c state in registers, MFMA C/D layout (col=lane&15,row=kg*4+r) ----
    float creg[2][4];
    #pragma unroll
    for (int j = 0; j < 2; ++j)
        #pragma unroll
        for (int r = 0; r < 4; ++r)
            creg[j][r] = c0[(size_t)(row0 + kg * 4 + r) * H_DIM + (w * 32 + j * 16 + n16)];

    // ---- initial A staging: x_0 (16x32) and h0 (16x256) ----
    {
        const int r = tid >> 5, cx = tid & 31;
        Alds[r * A_STRIDE + cx] =
            f2bf(warm[(size_t)(row0 + r) * (T_WARM * F_WARM) + cx]);     // t=0
    }
    #pragma unroll
    for (int e = 0; e < 8; ++e) {
        const int idx = tid + e * 512;                  // 0..4095
        const int r = idx >> 8, c = idx & 255;
        Alds[r * A_STRIDE + F_WARM + c] =
            f2bf(h0[(size_t)(row0 + r) * H_DIM + c]);
    }

    const short* abase = &Alds[n16 * A_STRIDE + kg * 8];
    const short* hbase = &Alds[n16 * A_STRIDE + F_WARM + kg * 8];

    for (int t = 0; t < T_TOTAL; ++t) {
        __syncthreads();                                // A tile ready

        // ---- z = [x|h] @ W : 9 k-steps x 4 gates x 2 n-tiles ----
        float4v acc[4][2];
        #pragma unroll
        for (int g = 0; g < 4; ++g)
            #pragma unroll
            for (int j = 0; j < 2; ++j)
                acc[g][j] = (float4v){bias[g][j], bias[g][j], bias[g][j], bias[g][j]};
        #pragma unroll
        for (int kk = 0; kk < 9; ++kk) {
            const short8 af = *(const short8*)(abase + kk * 32);
            #pragma unroll
            for (int g = 0; g < 4; ++g)
                #pragma unroll
                for (int j = 0; j < 2; ++j)
                    acc[g][j] = __builtin_amdgcn_mfma_f32_16x16x32_bf16(
                                    af, bw[g][j][kk], acc[g][j], 0, 0, 0);
        }

        // ---- gates + c/h update (registers only) ----
        float hval[2][4];
        #pragma unroll
        for (int j = 0; j < 2; ++j) {
            #pragma unroll
            for (int r = 0; r < 4; ++r) {
                const float ig = sigmoid_(acc[0][j][r]);
                const float fg = sigmoid_(acc[1][j][r]);
                const float gg = tanh_(acc[2][j][r]);
                const float og = sigmoid_(acc[3][j][r]);
                const float cc = fg * creg[j][r] + ig * gg;
                creg[j][r] = cc;
                hval[j][r] = og * tanh_(cc);
            }
        }

        __syncthreads();                                // all A reads done

        // ---- write h into A-LDS h region; stage x_{t+1} (non-feedback) ----
        #pragma unroll
        for (int j = 0; j < 2; ++j)
            #pragma unroll
            for (int r = 0; r < 4; ++r)
                Alds[(kg * 4 + r) * A_STRIDE + F_WARM + w * 32 + j * 16 + n16] =
                    f2bf(hval[j][r]);

        if (t + 1 < T_TOTAL) {
            const int tn = t + 1;
            const int r = tid >> 5, cx = tid & 31;
            if (tn < T_WARM) {
                Alds[r * A_STRIDE + cx] =
                    f2bf(warm[(size_t)(row0 + r) * (T_WARM * F_WARM)
                              + (size_t)tn * F_WARM + cx]);
            } else if (cx < F_AUTO) {
                Alds[r * A_STRIDE + cx] =
                    f2bf(autoin[(size_t)(row0 + r) * (T_WARM * F_AUTO)
                                + (size_t)(tn - T_WARM) * F_AUTO + cx]);
            }
        }

        __syncthreads();                                // h region complete

        // ---- wave 0: y_t = h_t @ W_out + b_out via MFMA ----
        if (w == 0) {
            float4v yacc = (float4v){bout_r, bout_r, bout_r, bout_r};
            #pragma unroll
            for (int kk = 0; kk < 8; ++kk)
                yacc = __builtin_amdgcn_mfma_f32_16x16x32_bf16(
                           *(const short8*)(hbase + kk * 32), wo[kk], yacc, 0, 0, 0);
            if (n16 < O_DIM) {
                #pragma unroll
                for (int r = 0; r < 4; ++r) {
                    const int row = kg * 4 + r;
                    const float y = yacc[r];
                    ybuf[row * O_DIM + n16] = y;
                    out[(size_t)(row0 + row) * (T_TOTAL * O_DIM)
                        + (size_t)t * O_DIM + n16] = y;
                }
            }
        }

        __syncthreads();                                // ybuf ready

        // ---- feedback: auto-phase x cols [24,32) = y_t ----
        if (t + 1 >= T_WARM && t + 1 < T_TOTAL && tid < 128) {
            const int r = tid >> 3, fo = tid & 7;
            Alds[r * A_STRIDE + F_AUTO + fo] = f2bf(ybuf[r * O_DIM + fo]);
        }
        // loop-top __syncthreads publishes staged A
    }
}

extern "C" void kernel_launch(void* const* d_in, const int* in_sizes, int n_in,
                              void* d_out, int out_size, void* d_ws, size_t ws_size,
                              hipStream_t stream) {
    (void)in_sizes; (void)n_in; (void)out_size; (void)d_ws; (void)ws_size;
    const float* c0   = (const float*)d_in[0];
    const float* h0   = (const float*)d_in[1];
    const float* warm = (const float*)d_in[2];
    const float* aut  = (const float*)d_in[3];
    const float* Wih  = (const float*)d_in[4];
    const float* Whh  = (const float*)d_in[5];
    const float* b    = (const float*)d_in[6];
    const float* Wout = (const float*)d_in[7];
    const float* bout = (const float*)d_in[8];
    float* out = (float*)d_out;

    hipLaunchKernelGGL(lstm_wg, dim3(64), dim3(512), 0, stream,
                       c0, h0, warm, aut, Wih, Whh, b, Wout, bout, out);
}

// Round 4
// 8665.453 us; speedup vs baseline: 1.4801x; 1.4801x over previous
//
#include <hip/hip_runtime.h>
#include <stdint.h>

// R4: 64 WGs x 256 threads (4 waves, 1 wave/SIMD => 512-VGPR budget per wave).
// R3 failure: 512-thread block caps waves at 256 VGPRs -> compiler spilled the
// entire 288-VGPR weight array to scratch (VGPR_Count=128, 12.5us/step).
// R4: wave owns 64 h-units x 4 gates (16 MFMA col-tiles). Weights: 108 frags
// (432 VGPRs) in registers + 36 frags (144 KB) in LDS. acc held to 32 VGPRs
// via a 2-pass j-loop; h packed to bf16 in 8 regs. W_out frags staged in d_ws.
// No cross-WG communication; plain launch.

#define B_TOTAL   1024
#define H_DIM     256
#define F_WARM    32
#define F_AUTO    24
#define O_DIM     8
#define T_WARM    512
#define T_TOTAL   1024
#define N4H       1024
#define A_STRIDE  296   // bf16 elems/row: 592 B, 16B-aligned, ~2-way banks

typedef __attribute__((ext_vector_type(8))) short short8;
typedef __attribute__((ext_vector_type(4))) float float4v;

__device__ __forceinline__ short f2bf(float x) {
    union { float f; uint32_t u; } v; v.f = x;
    uint32_t r = v.u + 0x7FFFu + ((v.u >> 16) & 1u);   // RNE
    return (short)(r >> 16);
}
__device__ __forceinline__ float sigmoid_(float x) {
    const float e = __expf(-x);
    return __builtin_amdgcn_rcpf(1.0f + e);
}
__device__ __forceinline__ float tanh_(float x) {
    const float e = __expf(-2.0f * fabsf(x));
    const float t = (1.0f - e) * __builtin_amdgcn_rcpf(1.0f + e);
    return x >= 0.0f ? t : -t;
}

__global__ __launch_bounds__(256, 1)
void lstm_wg(const float* __restrict__ c0, const float* __restrict__ h0,
             const float* __restrict__ warm, const float* __restrict__ autoin,
             const float* __restrict__ W_ih, const float* __restrict__ W_hh,
             const float* __restrict__ bvec, const float* __restrict__ W_out,
             const float* __restrict__ b_out, float* __restrict__ out,
             unsigned short* __restrict__ ws)
{
    const int tid  = threadIdx.x;
    const int w    = tid >> 6;        // wave 0..3 -> h-units [w*64, w*64+64)
    const int l    = tid & 63;
    const int n16  = l & 15;          // MFMA n (B/D col) / A row (m)
    const int kg   = l >> 4;          // k-group 0..3
    const int row0 = blockIdx.x * 16; // batch rows [row0, row0+16)

    // LDS: weights 144 KB + A-tile + bias + ybuf = 161536 B (< 160 KiB)
    __shared__ __align__(16) short WLs[73728];          // 144 blocks x 1 KB
    __shared__ __align__(16) short Alds[16 * A_STRIDE]; // [x(32) | h(256) | pad]
    __shared__ float biasL[N4H];
    __shared__ float ybuf[16 * O_DIM];

    // ---- LDS weight blocks: kk in {7,8} all gates + (kk=6,g=3) ----
    // block bi: kk7 -> g*16+w*4+j ; kk8 -> 64+... ; kk6g3 -> 128 + w*4 + j
    for (int idx = tid; idx < 73728; idx += 256) {
        const int i    = idx & 7;
        const int lane = (idx >> 3) & 63;
        const int bi   = idx >> 9;
        int kk, g, wq, j;
        if (bi < 128) { kk = 7 + (bi >> 6); const int r6 = bi & 63;
                        g = r6 >> 4; wq = (r6 >> 2) & 3; j = r6 & 3; }
        else          { kk = 6; g = 3; wq = (bi - 128) >> 2; j = (bi - 128) & 3; }
        const int k   = kk * 32 + (lane >> 4) * 8 + i;
        const int col = g * 256 + wq * 64 + j * 16 + (lane & 15);
        const float wv = (k < F_WARM) ? W_ih[k * N4H + col]
                                      : W_hh[(k - F_WARM) * N4H + col];
        WLs[idx] = f2bf(wv);
    }
    for (int e = 0; e < 4; ++e) biasL[tid + e * 256] = bvec[tid + e * 256];

    // ---- W_out MFMA B-frags -> this WG's d_ws region (8 KB) ----
    unsigned short* wsW = ws + (size_t)blockIdx.x * 4096;
    for (int idx = tid; idx < 4096; idx += 256) {
        const int i = idx & 7, lane = (idx >> 3) & 63, kk = idx >> 9;
        const int k = kk * 32 + (lane >> 4) * 8 + i;
        const int n = lane & 15;
        wsW[idx] = (unsigned short)((n < O_DIM) ? f2bf(W_out[k * O_DIM + n]) : (short)0);
    }

    // ---- register weights: kk 0..5 all gates + kk=6 g 0..2 (432 VGPRs) ----
    short8 bwr[4][4][6];
    short8 bw6[3][4];
    #pragma unroll
    for (int g = 0; g < 4; ++g)
        #pragma unroll
        for (int j = 0; j < 4; ++j) {
            const int col = g * 256 + w * 64 + j * 16 + n16;
            #pragma unroll
            for (int kk = 0; kk < 6; ++kk) {
                short8 f;
                #pragma unroll
                for (int i = 0; i < 8; ++i) {
                    const int k = kk * 32 + kg * 8 + i;
                    const float wv = (k < F_WARM) ? W_ih[k * N4H + col]
                                                  : W_hh[(k - F_WARM) * N4H + col];
                    f[i] = f2bf(wv);
                }
                bwr[g][j][kk] = f;
            }
        }
    #pragma unroll
    for (int g = 0; g < 3; ++g)
        #pragma unroll
        for (int j = 0; j < 4; ++j) {
            const int col = g * 256 + w * 64 + j * 16 + n16;
            short8 f;
            #pragma unroll
            for (int i = 0; i < 8; ++i) {
                const int k = 192 + kg * 8 + i;     // kk=6
                f[i] = f2bf(W_hh[(k - F_WARM) * N4H + col]);
            }
            bw6[g][j] = f;
        }

    const float bout = (w == 0 && n16 < O_DIM) ? b_out[n16] : 0.0f;

    // ---- c state: MFMA C/D layout (col=lane&15, row=kg*4+r) ----
    float creg[4][4];
    #pragma unroll
    for (int j = 0; j < 4; ++j)
        #pragma unroll
        for (int r = 0; r < 4; ++r)
            creg[j][r] = c0[(size_t)(row0 + kg * 4 + r) * H_DIM + (w * 64 + j * 16 + n16)];

    // ---- initial A staging: x_0 (16x32) + h0 (16x256) ----
    #pragma unroll
    for (int e = 0; e < 2; ++e) {
        const int idx = tid + e * 256;
        const int r = idx >> 5, cx = idx & 31;
        Alds[r * A_STRIDE + cx] =
            f2bf(warm[(size_t)(row0 + r) * (T_WARM * F_WARM) + cx]);   // t=0
    }
    #pragma unroll
    for (int e = 0; e < 16; ++e) {
        const int idx = tid + e * 256;
        const int r = idx >> 8, c = idx & 255;
        Alds[r * A_STRIDE + F_WARM + c] = f2bf(h0[(size_t)(row0 + r) * H_DIM + c]);
    }

    const short* abase = &Alds[n16 * A_STRIDE + kg * 8];
    const short* hbase = &Alds[n16 * A_STRIDE + F_WARM + kg * 8];
    const short8* wsW8 = (const short8*)wsW;

    for (int t = 0; t < T_TOTAL; ++t) {
        __syncthreads();                                // A tile ready

        uint32_t hp[8];                                 // packed bf16 h (16 vals)

        #pragma unroll
        for (int jp = 0; jp < 2; ++jp) {
            // ---- K-loop: 9 chunks x 4 gates x 2 j-tiles ----
            float4v acc[4][2];
            #pragma unroll
            for (int g = 0; g < 4; ++g)
                #pragma unroll
                for (int jj = 0; jj < 2; ++jj)
                    acc[g][jj] = (float4v){0.f, 0.f, 0.f, 0.f};

            #pragma unroll
            for (int kk = 0; kk < 9; ++kk) {
                const short8 af = *(const short8*)(abase + kk * 32);
                #pragma unroll
                for (int g = 0; g < 4; ++g)
                    #pragma unroll
                    for (int jj = 0; jj < 2; ++jj) {
                        const int j = jp * 2 + jj;
                        short8 bf;
                        if (kk <= 5)                bf = bwr[g][j][kk];
                        else if (kk == 6 && g < 3)  bf = bw6[g][j];
                        else {
                            const int bi = (kk >= 7) ? ((kk - 7) * 64 + g * 16 + w * 4 + j)
                                                     : (128 + w * 4 + j);
                            bf = *(const short8*)&WLs[bi * 512 + l * 8];
                        }
                        acc[g][jj] = __builtin_amdgcn_mfma_f32_16x16x32_bf16(
                                         af, bf, acc[g][jj], 0, 0, 0);
                    }
            }

            // ---- gates + c/h update for this j-pair ----
            #pragma unroll
            for (int jj = 0; jj < 2; ++jj) {
                const int j  = jp * 2 + jj;
                const int cb = w * 64 + j * 16 + n16;
                const float b0 = biasL[cb];
                const float b1 = biasL[256 + cb];
                const float b2 = biasL[512 + cb];
                const float b3 = biasL[768 + cb];
                uint32_t u0 = 0, u1 = 0;
                #pragma unroll
                for (int r = 0; r < 4; ++r) {
                    const float ig = sigmoid_(acc[0][jj][r] + b0);
                    const float fg = sigmoid_(acc[1][jj][r] + b1);
                    const float gg = tanh_(acc[2][jj][r] + b2);
                    const float og = sigmoid_(acc[3][jj][r] + b3);
                    const float cc = fg * creg[j][r] + ig * gg;
                    creg[j][r] = cc;
                    const float hh = og * tanh_(cc);
                    const uint32_t hb = (uint32_t)(uint16_t)f2bf(hh);
                    if (r == 0) u0 = hb;        else if (r == 1) u0 |= hb << 16;
                    else if (r == 2) u1 = hb;   else             u1 |= hb << 16;
                }
                hp[jp * 4 + jj * 2 + 0] = u0;
                hp[jp * 4 + jj * 2 + 1] = u1;
            }
        }

        __syncthreads();                                // all A reads done

        // ---- write h_t into A-LDS; stage x_{t+1} (non-feedback cols) ----
        #pragma unroll
        for (int jp2 = 0; jp2 < 2; ++jp2)
            #pragma unroll
            for (int jj = 0; jj < 2; ++jj)
                #pragma unroll
                for (int rp = 0; rp < 2; ++rp) {
                    const uint32_t u = hp[jp2 * 4 + jj * 2 + rp];
                    const int col = F_WARM + w * 64 + (jp2 * 2 + jj) * 16 + n16;
                    Alds[(kg * 4 + rp * 2 + 0) * A_STRIDE + col] = (short)(u & 0xFFFF);
                    Alds[(kg * 4 + rp * 2 + 1) * A_STRIDE + col] = (short)(u >> 16);
                }

        if (t + 1 < T_TOTAL) {
            const int tn = t + 1;
            #pragma unroll
            for (int e = 0; e < 2; ++e) {
                const int idx = tid + e * 256;
                const int r = idx >> 5, cx = idx & 31;
                if (tn < T_WARM) {
                    Alds[r * A_STRIDE + cx] =
                        f2bf(warm[(size_t)(row0 + r) * (T_WARM * F_WARM)
                                  + (size_t)tn * F_WARM + cx]);
                } else if (cx < F_AUTO) {
                    Alds[r * A_STRIDE + cx] =
                        f2bf(autoin[(size_t)(row0 + r) * (T_WARM * F_AUTO)
                                    + (size_t)(tn - T_WARM) * F_AUTO + cx]);
                }
            }
        }

        __syncthreads();                                // h region complete

        // ---- wave 0: y_t = h_t @ W_out + b_out via MFMA (frags from d_ws) ----
        if (w == 0) {
            float4v ya = (float4v){bout, bout, bout, bout};
            #pragma unroll
            for (int kk = 0; kk < 8; ++kk)
                ya = __builtin_amdgcn_mfma_f32_16x16x32_bf16(
                         *(const short8*)(hbase + kk * 32), wsW8[kk * 64 + l], ya, 0, 0, 0);
            if (n16 < O_DIM) {
                #pragma unroll
                for (int r = 0; r < 4; ++r) {
                    const int row = kg * 4 + r;
                    const float y = ya[r];
                    ybuf[row * O_DIM + n16] = y;
                    out[(size_t)(row0 + row) * (T_TOTAL * O_DIM)
                        + (size_t)t * O_DIM + n16] = y;
                }
            }
        }

        __syncthreads();                                // ybuf ready

        // ---- feedback: auto-phase x cols [24,32) = y_t ----
        if (t + 1 >= T_WARM && t + 1 < T_TOTAL && tid < 128) {
            const int r = tid >> 3, fo = tid & 7;
            Alds[r * A_STRIDE + F_AUTO + fo] = f2bf(ybuf[r * O_DIM + fo]);
        }
        // loop-top __syncthreads publishes staged A
    }
}

extern "C" void kernel_launch(void* const* d_in, const int* in_sizes, int n_in,
                              void* d_out, int out_size, void* d_ws, size_t ws_size,
                              hipStream_t stream) {
    (void)in_sizes; (void)n_in; (void)out_size; (void)ws_size;
    const float* c0   = (const float*)d_in[0];
    const float* h0   = (const float*)d_in[1];
    const float* warm = (const float*)d_in[2];
    const float* aut  = (const float*)d_in[3];
    const float* Wih  = (const float*)d_in[4];
    const float* Whh  = (const float*)d_in[5];
    const float* b    = (const float*)d_in[6];
    const float* Wout = (const float*)d_in[7];
    const float* bout = (const float*)d_in[8];
    float* out = (float*)d_out;
    unsigned short* ws = (unsigned short*)d_ws;   // 64 WGs x 8 KB W_out frags

    hipLaunchKernelGGL(lstm_wg, dim3(64), dim3(256), 0, stream,
                       c0, h0, warm, aut, Wih, Whh, b, Wout, bout, out, ws);
}